// Round 2
// baseline (3153.232 us; speedup 1.0000x reference)
//
#include <hip/hip_runtime.h>
#include <hip/hip_bf16.h>

// LSTM decoder: L=2, B=64, T=512, H=IN=512, gates G=2048 (i,f,g,o).
// Round 8: L2-mediated h exchange.
//  - h loads are sc0-only (L2-cacheable); one buffer_inv sc1 per step,
//    executed by wave 0 strictly AFTER barrier-detect (double-sync), before
//    any h load. 16 blocks/XCD share each MALL fetch through L2: MALL read
//    traffic drops ~10x (20 MB/step -> ~2 MB/step), h loads ~900cy -> ~150cy.
//  - stores stay write-through sc0 sc1 (data at MALL before counter++).
//  - ALL out stores (rows + finals) switched to sc0 sc1 write-through:
//    buffer_inv drops dirty L2 lines, so no plain/nontemporal global stores
//    may exist while invs are firing.
//  - layer-decoupled structure from round 7 kept (neutral, composes fine).
// Numerics = validated rounds 2-5: ih single bf16, hh hi+lo W x hi+lo h.

#define TT 512

using short8 = __attribute__((ext_vector_type(8))) short;
using f32x4  = __attribute__((ext_vector_type(4))) float;

__device__ __forceinline__ short f2bf(float f) {
  unsigned u = __float_as_uint(f);
  u = (u + 0x7fffu + ((u >> 16) & 1u)) >> 16;  // RNE
  return (short)u;
}
__device__ __forceinline__ float bf2f(short s) {
  return __uint_as_float(((unsigned)(unsigned short)s) << 16);
}
__device__ __forceinline__ float sigf(float x) { return 1.f / (1.f + __expf(-x)); }
__device__ __forceinline__ float tanh_(float x) { return 1.f - 2.f / (__expf(2.f * x) + 1.f); }

// 8 device-coherent-read 16B loads, L2-CACHEABLE (sc0: bypass L1 only).
// Freshness is provided by the per-step buffer_inv sc1 in gwait.
__device__ __forceinline__ void ld8_nw(short8* d,
    const short* p0, const short* p1, const short* p2, const short* p3,
    const short* p4, const short* p5, const short* p6, const short* p7) {
  asm volatile(
      "global_load_dwordx4 %0, %8, off sc0\n\t"
      "global_load_dwordx4 %1, %9, off sc0\n\t"
      "global_load_dwordx4 %2, %10, off sc0\n\t"
      "global_load_dwordx4 %3, %11, off sc0\n\t"
      "global_load_dwordx4 %4, %12, off sc0\n\t"
      "global_load_dwordx4 %5, %13, off sc0\n\t"
      "global_load_dwordx4 %6, %14, off sc0\n\t"
      "global_load_dwordx4 %7, %15, off sc0"
      : "=&v"(d[0]), "=&v"(d[1]), "=&v"(d[2]), "=&v"(d[3]),
        "=&v"(d[4]), "=&v"(d[5]), "=&v"(d[6]), "=&v"(d[7])
      : "v"(p0), "v"(p1), "v"(p2), "v"(p3),
        "v"(p4), "v"(p5), "v"(p6), "v"(p7)
      : "memory");
}

// tie a waitcnt (or nothing) to 8 loaded fragments so no use precedes it
#define TIE8(A, CNT)                                                        \
  asm volatile(CNT : "+v"(A[0]), "+v"(A[1]), "+v"(A[2]), "+v"(A[3]),        \
                     "+v"(A[4]), "+v"(A[5]), "+v"(A[6]), "+v"(A[7])         \
               ::"memory")

// coherent write-through stores (reach MALL; never dirty in L2)
__device__ __forceinline__ void stc_short(short* p, short v) {
  asm volatile("global_store_short %0, %1, off sc0 sc1"
               :: "v"(p), "v"((int)v) : "memory");
}
__device__ __forceinline__ void stc_float(float* p, float v) {
  asm volatile("global_store_dword %0, %1, off sc0 sc1"
               :: "v"(p), "v"(v) : "memory");
}

// per-XCD L2 invalidate (tag flash; MALL holds the coherent copy)
__device__ __forceinline__ void l2inv() {
  asm volatile("buffer_inv sc1" ::: "memory");
}

// ---- x fp32 [64][512][512] -> bf16 in first half of each out row ----
__global__ __launch_bounds__(256) void conv_x(const float* __restrict__ x,
                                              short* __restrict__ xo) {
  size_t g = (size_t)blockIdx.x * 256 + threadIdx.x;  // 2,097,152
  size_t i = g * 8;
  float4 v0 = *(const float4*)(x + i);
  float4 v1 = *(const float4*)(x + i + 4);
  short8 r;
  r[0] = f2bf(v0.x); r[1] = f2bf(v0.y); r[2] = f2bf(v0.z); r[3] = f2bf(v0.w);
  r[4] = f2bf(v1.x); r[5] = f2bf(v1.y); r[6] = f2bf(v1.z); r[7] = f2bf(v1.w);
  *(short8*)(xo + (i >> 9) * 1024 + (i & 511)) = r;
}

// ---- W pack: per-block contiguous LDS image (49152 shorts per (l,j8)) ----
__global__ __launch_bounds__(256) void conv_w(const float* __restrict__ Wih,
                                              const float* __restrict__ Whh,
                                              short* __restrict__ wp) {
  int g = blockIdx.x * 256 + threadIdx.x;  // 0..786431
  int l = g / 393216;
  int rem = g % 393216;
  int j8 = rem / 6144;
  int q8 = rem % 6144;
  int s, hl, bt, c, lane;
  if (q8 < 2048) {
    s = 0; hl = 0;
    int seg = q8 >> 6; bt = seg >> 4; c = seg & 15; lane = q8 & 63;
  } else {
    int q = q8 - 2048;
    s = 1;
    int seg = q >> 6; bt = seg >> 5; c = (seg >> 1) & 15; hl = seg & 1;
    lane = q & 63;
  }
  int r = lane & 15;
  int gg = r >> 2, jj = r & 3;
  int R = gg * 512 + j8 * 8 + bt * 4 + jj;
  int k = c * 32 + (lane >> 4) * 8;
  const float* src = (s ? Whh : Wih) + ((size_t)(l * 2048 + R)) * 512 + k;
  short8 o;
#pragma unroll
  for (int e = 0; e < 8; ++e) {
    float v = src[e];
    short hi = f2bf(v);
    o[e] = hl ? f2bf(v - bf2f(hi)) : hi;
  }
  *(short8*)(wp + (size_t)g * 8) = o;
}

// ---- h0 -> ring slots (L0 init -> slot 3, L1 init -> slot 5) -------------
// hhi/hlo layout: [6 slots][k8=64][b=64][e=8]; slots 0-3 L0 ring, 4-5 L1.
__global__ __launch_bounds__(256) void init_state(const float* __restrict__ h0,
                                                  short* __restrict__ hhi,
                                                  short* __restrict__ hlo,
                                                  unsigned* __restrict__ bar) {
  int i = blockIdx.x * 256 + threadIdx.x;  // 0..65535 [l][b][j]
  int l = i >> 15, bj = i & 32767;
  int b = bj >> 9, j = bj & 511;
  float h = h0[i];
  short hi = f2bf(h);
  int slot = l ? 5 : 3;  // (-1) mod ring
  int o = slot * 32768 + (j >> 3) * 512 + b * 8 + (j & 7);
  hhi[o] = hi;
  hlo[o] = f2bf(h - bf2f(hi));
  if (blockIdx.x < 8) bar[blockIdx.x * 256 + threadIdx.x] = 0u;
}

// ---- split-phase fence-free per-layer barriers ----
// gwait ends with: sync (all past detect) -> wave0 L2-inv -> sync -> loads.
__device__ __forceinline__ void garrive(unsigned* cnt, int tid, int slot) {
  __syncthreads();  // drains coherent h stores (vmcnt(0) before s_barrier)
  if (tid == 0)
    __hip_atomic_fetch_add(&cnt[slot * 32], 1u, __ATOMIC_RELAXED,
                           __HIP_MEMORY_SCOPE_AGENT);
}
__device__ __forceinline__ void gwait1(unsigned* c1, unsigned t1, int tid) {
  if (tid == 0) {
    for (;;) {
      unsigned s1 = 0;
#pragma unroll
      for (int r = 0; r < 32; ++r)
        s1 += __hip_atomic_load(&c1[r * 32], __ATOMIC_RELAXED,
                                __HIP_MEMORY_SCOPE_AGENT);
      if (s1 >= t1) break;
      __builtin_amdgcn_s_sleep(1);
    }
  }
  __syncthreads();            // all waves past detect
  if (tid < 64) l2inv();      // wave 0: flash-invalidate local L2
  __syncthreads();            // h loads strictly after inv
}
__device__ __forceinline__ void gwait2(unsigned* c1, unsigned t1,
                                       unsigned* c2, unsigned t2, int tid) {
  if (tid == 0) {
    for (;;) {
      unsigned s1 = 0, s2 = 0;
#pragma unroll
      for (int r = 0; r < 32; ++r) {
        s1 += __hip_atomic_load(&c1[r * 32], __ATOMIC_RELAXED,
                                __HIP_MEMORY_SCOPE_AGENT);
        s2 += __hip_atomic_load(&c2[r * 32], __ATOMIC_RELAXED,
                                __HIP_MEMORY_SCOPE_AGENT);
      }
      if (s1 >= t1 && s2 >= t2) break;
      __builtin_amdgcn_s_sleep(1);
    }
  }
  __syncthreads();
  if (tid < 64) l2inv();
  __syncthreads();
}

// ---- persistent LSTM ----------------------------------------------------
// grid 128 = [layer(2)][j8(64)]; block 512 = 8 waves (kq = wv&3, ah = wv>>2).
// dyn LDS 132096B: [0,98304) W image; [98304,..) float sG[4][32][66].
__global__ __launch_bounds__(512, 1) void lstm_persist(
    const short* __restrict__ wp, const float* __restrict__ c0,
    const float* __restrict__ bih, const float* __restrict__ bhh,
    short* __restrict__ hhi, short* __restrict__ hlo,
    unsigned* __restrict__ bar, float* __restrict__ out) {
  extern __shared__ char smem[];
  short* lw = (short*)smem;             // 49152 shorts
  float* sG = (float*)(smem + 98304);   // [kq][s][b] stride 66

  const int tid = threadIdx.x;
  const int layer = blockIdx.x >> 6;
  const int j8 = blockIdx.x & 63;
  const int bslot = blockIdx.x & 31;    // 2 blocks per padded counter
  unsigned* cntMy = bar + (layer << 10);        // own layer's 32 counters
  unsigned* cntOt = bar + ((layer ^ 1) << 10);  // other layer's
  const int wv = tid >> 6;
  const int kq = wv & 3;
  const int ah = wv >> 2;
  const int lane = tid & 63;
  const int m = lane & 15;
  const int koq = lane >> 4;
  const int cbase = kq << 2;

  {  // W slice -> LDS (one-time)
    const short* src = wp + (size_t)(layer * 64 + j8) * 49152;
    for (int i = tid; i < 6144; i += 512)
      *(short8*)(lw + i * 8) = *(const short8*)(src + i * 8);
  }

  const int sb = tid >> 3, sj = tid & 7;
  const int j = (j8 << 3) + sj;
  float creg = c0[layer * 32768 + sb * 512 + j];
  float hf = 0.f;
  float bsum[4];
#pragma unroll
  for (int g = 0; g < 4; ++g)
    bsum[g] = bih[layer * 2048 + g * 512 + j] + bhh[layer * 2048 + g * 512 + j];
  __syncthreads();

  const int br0 = ((ah * 2 + 0) << 4) + m;
  const int br1 = ((ah * 2 + 1) << 4) + m;
  const short* xo = (const short*)out;

  f32x4 acc[2][2];

  auto zacc = [&]() {
#pragma unroll
    for (int u = 0; u < 2; ++u)
#pragma unroll
      for (int v = 0; v < 2; ++v) acc[u][v] = f32x4{0.f, 0.f, 0.f, 0.f};
  };

#define PA(rX, cc, br) \
  ((rX) + ((((cbase + (cc)) << 2) + koq) << 9) + (br) * 8)

  // layer-0 ih for a given timestep from bf16 x rows (B-frags from LDS)
  auto ih_l0 = [&](int txt) {
#pragma unroll
    for (int cc = 0; cc < 4; ++cc) {
      const int c = cbase + cc;
      const int k = c * 32 + (koq << 3);
      short8 b0 = *(const short8*)(lw + c * 512 + lane * 8);
      short8 b1 = *(const short8*)(lw + (16 + c) * 512 + lane * 8);
#pragma unroll
      for (int it = 0; it < 2; ++it) {
        const int br = it ? br1 : br0;
        short8 a = *(const short8*)(xo + ((size_t)br * TT + txt) * 1024 + k);
        acc[0][it] = __builtin_amdgcn_mfma_f32_16x16x32_bf16(a, b0, acc[0][it], 0, 0, 0);
        acc[1][it] = __builtin_amdgcn_mfma_f32_16x16x32_bf16(a, b1, acc[1][it], 0, 0, 0);
      }
    }
  };

  // layer-1 ih from an h0 ring slot (hi only; validated numerics).
  // Caller guarantees the preceding gwait's L2-inv ordering.
  auto ih_l1 = [&](const short* ph) {
    short8 Ax[8];
    ld8_nw(Ax, PA(ph, 0, br0), PA(ph, 0, br1), PA(ph, 1, br0), PA(ph, 1, br1),
               PA(ph, 2, br0), PA(ph, 2, br1), PA(ph, 3, br0), PA(ph, 3, br1));
    TIE8(Ax, "s_waitcnt vmcnt(0)");
#pragma unroll
    for (int cc = 0; cc < 4; ++cc) {
      const int c = cbase + cc;
      short8 b0 = *(const short8*)(lw + c * 512 + lane * 8);
      short8 b1 = *(const short8*)(lw + (16 + c) * 512 + lane * 8);
#pragma unroll
      for (int it = 0; it < 2; ++it) {
        short8 a = Ax[cc * 2 + it];
        acc[0][it] = __builtin_amdgcn_mfma_f32_16x16x32_bf16(a, b0, acc[0][it], 0, 0, 0);
        acc[1][it] = __builtin_amdgcn_mfma_f32_16x16x32_bf16(a, b1, acc[1][it], 0, 0, 0);
      }
    }
  };

  // shared per-step body: hh (hi+lo), partial reduce, cell update, h store.
  // acc must already hold ih(t). rh/rl = read slot bases; slotOut = write slot.
  auto stepBody = [&](const short* rh, const short* rl, int slotOut, int t) {
    short8 Ah[8], Al[8];
    ld8_nw(Ah, PA(rh, 0, br0), PA(rh, 0, br1), PA(rh, 1, br0), PA(rh, 1, br1),
               PA(rh, 2, br0), PA(rh, 2, br1), PA(rh, 3, br0), PA(rh, 3, br1));
    ld8_nw(Al, PA(rl, 0, br0), PA(rl, 0, br1), PA(rl, 1, br0), PA(rl, 1, br1),
               PA(rl, 2, br0), PA(rl, 2, br1), PA(rl, 3, br0), PA(rl, 3, br1));
    TIE8(Ah, "s_waitcnt vmcnt(0)");
    TIE8(Al, "");

    // ---- hh: hi+lo W x hi+lo h (3 MFMA) ----
#pragma unroll
    for (int cc = 0; cc < 4; ++cc) {
      const int c = cbase + cc;
      short8 bh0 = *(const short8*)(lw + 16384 + (c * 2 + 0) * 512 + lane * 8);
      short8 bl0 = *(const short8*)(lw + 16384 + (c * 2 + 1) * 512 + lane * 8);
      short8 bh1 = *(const short8*)(lw + 16384 + ((16 + c) * 2 + 0) * 512 + lane * 8);
      short8 bl1 = *(const short8*)(lw + 16384 + ((16 + c) * 2 + 1) * 512 + lane * 8);
#pragma unroll
      for (int it = 0; it < 2; ++it) {
        short8 a = Ah[cc * 2 + it];
        short8 al = Al[cc * 2 + it];
        acc[0][it] = __builtin_amdgcn_mfma_f32_16x16x32_bf16(a, bh0, acc[0][it], 0, 0, 0);
        acc[0][it] = __builtin_amdgcn_mfma_f32_16x16x32_bf16(a, bl0, acc[0][it], 0, 0, 0);
        acc[0][it] = __builtin_amdgcn_mfma_f32_16x16x32_bf16(al, bh0, acc[0][it], 0, 0, 0);
        acc[1][it] = __builtin_amdgcn_mfma_f32_16x16x32_bf16(a, bh1, acc[1][it], 0, 0, 0);
        acc[1][it] = __builtin_amdgcn_mfma_f32_16x16x32_bf16(a, bl1, acc[1][it], 0, 0, 0);
        acc[1][it] = __builtin_amdgcn_mfma_f32_16x16x32_bf16(al, bh1, acc[1][it], 0, 0, 0);
      }
    }

    // ---- partials -> sG ----
#pragma unroll
    for (int bt = 0; bt < 2; ++bt)
#pragma unroll
      for (int it = 0; it < 2; ++it) {
        const int srow = bt * 16 + m;
        const int col = ((ah * 2 + it) << 4) + (koq << 2);
#pragma unroll
        for (int r = 0; r < 4; ++r)
          sG[(kq * 32 + srow) * 66 + col + r] = acc[bt][it][r];
      }
    __syncthreads();

    // ---- reduce + cell update ----
    {
      const int bt = sj >> 2, jl = sj & 3;
      float gv[4];
#pragma unroll
      for (int g = 0; g < 4; ++g) {
        const int s = bt * 16 + g * 4 + jl;
        gv[g] = sG[(0 * 32 + s) * 66 + sb] + sG[(1 * 32 + s) * 66 + sb] +
                sG[(2 * 32 + s) * 66 + sb] + sG[(3 * 32 + s) * 66 + sb] +
                bsum[g];
      }
      const float cn = sigf(gv[1]) * creg + sigf(gv[0]) * tanh_(gv[2]);
      const float hn = sigf(gv[3]) * tanh_(cn);
      creg = cn;
      hf = hn;
      const int ho = slotOut * 32768 + (j8 << 9) + tid;
      const short hb = f2bf(hn);
      stc_short(hhi + ho, hb);
      stc_short(hlo + ho, f2bf(hn - bf2f(hb)));
      if (layer)
        stc_float(&out[((size_t)sb * 512 + t) * 512 + j], hn);
    }
  };

  if (layer == 0) {
    // -------- layer 0: own 64-block barrier; 4-slot h0 ring --------
    zacc();
    ih_l0(0);  // prologue: ih(t=0) from x (init_state h visible at launch)
    for (int t = 0; t < TT; ++t) {
      if (t >= 4)
        // own: all L0 stored h0(t-1). guard: all L1 arrived step t-4, so
        // their Ax read of h0(t-4) (slot t&3, about to be overwritten) done.
        gwait2(cntMy, (unsigned)(64 * t), cntOt, (unsigned)(64 * (t - 3)), tid);
      else if (t >= 1)
        gwait1(cntMy, (unsigned)(64 * t), tid);
      const int ps = (t + 3) & 3;  // slot of h0(t-1); t=0 -> 3 = init
      stepBody(hhi + ps * 32768, hlo + ps * 32768, t & 3, t);
      garrive(cntMy, tid, bslot);
      if (t + 1 < TT) {  // overlap next ih with others' wait
        zacc();
        ih_l0(t + 1);
      }
    }
  } else {
    // -------- layer 1: own 64-block barrier; ih in post-arrive overlap ----
    zacc();
    gwait1(cntOt, 64u, tid);  // L0 finished step 0 -> h0(0) in slot 0 (+inv)
    ih_l1(hhi + 0 * 32768);
    for (int t = 0; t < TT; ++t) {
      if (t >= 1) gwait1(cntMy, (unsigned)(64 * t), tid);
      const int ps = 4 + ((t + 1) & 1);  // slot of h1(t-1); t=0 -> 5 = init
      stepBody(hhi + ps * 32768, hlo + ps * 32768, 4 + (t & 1), t);
      garrive(cntMy, tid, bslot);
      if (t + 1 < TT) {
        // h0(t+1) needed: wait L0 finished step t+1 (normally already true,
        // includes the L2-inv), then Ax + ih in the shadow of stragglers.
        gwait1(cntOt, (unsigned)(64 * (t + 2)), tid);
        zacc();
        ih_l1(hhi + ((t + 1) & 3) * 32768);
      }
    }
  }

  // finals from registers (write-through: later same-XCD invs must not be
  // able to drop dirty lines of ours)
  stc_float(&out[16777216 + layer * 32768 + sb * 512 + j], hf);
  stc_float(&out[16777216 + 65536 + layer * 32768 + sb * 512 + j], creg);
}

// ---- host ---------------------------------------------------------------

extern "C" void kernel_launch(void* const* d_in, const int* in_sizes, int n_in,
                              void* d_out, int out_size, void* d_ws,
                              size_t ws_size, hipStream_t stream) {
  const float* x = (const float*)d_in[0];
  const float* h0 = (const float*)d_in[1];
  const float* c0 = (const float*)d_in[2];
  const float* Wih = (const float*)d_in[3];
  const float* Whh = (const float*)d_in[4];
  const float* bih = (const float*)d_in[5];
  const float* bhh = (const float*)d_in[6];
  float* out = (float*)d_out;

  char* ws = (char*)d_ws;
  short* wp = (short*)(ws + 0);             // 12 MB  fragment-packed W images
  short* hhi = (short*)(ws + 12582912);     // 384 KB h hi [6 slots][k8][b][8]
  short* hlo = (short*)(ws + 12976128);     // 384 KB h lo
  unsigned* bar = (unsigned*)(ws + 13369344);  // 8 KB: 2 x 32 padded counters
  // total ws use: ~12.8 MB

  hipFuncSetAttribute(reinterpret_cast<const void*>(lstm_persist),
                      hipFuncAttributeMaxDynamicSharedMemorySize, 132096);

  conv_x<<<8192, 256, 0, stream>>>(x, (short*)out);
  conv_w<<<3072, 256, 0, stream>>>(Wih, Whh, wp);
  init_state<<<256, 256, 0, stream>>>(h0, hhi, hlo, bar);

  void* args[] = {(void*)&wp,  (void*)&c0,  (void*)&bih, (void*)&bhh,
                  (void*)&hhi, (void*)&hlo, (void*)&bar, (void*)&out};
  hipLaunchCooperativeKernel(reinterpret_cast<void*>(lstm_persist), dim3(128),
                             dim3(512), args, 132096, stream);
}

// Round 5
// 3043.336 us; speedup vs baseline: 1.0361x; 1.0361x over previous
//
#include <hip/hip_runtime.h>
#include <hip/hip_bf16.h>

// LSTM decoder: L=2, B=64, T=512, H=IN=512, gates G=2048 (i,f,g,o).
// Round 10 = Round 9 + deadlock fix (r4's hang): L1's final shadow wait
// (t+2 == TT) polled flag0 >= 512, a value L0's leader never publishes
// (flags stop at 511). Fix: final shadow read uses the self-inv path.
// ---------------------------------------------------------------------
// L2-mediated h exchange with PER-XCD LEADER invalidation.
//  - r8 post-mortem: per-block buffer_inv (128/step) was an inv STORM --
//    each inv dropped neighbors' freshly cached h lines (FETCH unchanged),
//    plus de-cached x rows. Mechanism right, implementation wrong.
//  - r9: one leader per (layer, XCD), elected once at startup via
//    s_getreg(HW_REG_XCC_ID) + atomic claim. Per step: leader invs L2
//    (buffer_inv sc1 + vmcnt(0)) then bumps flag[layer][xcd]; same-XCD
//    blocks poll the flag, then issue sc0 (L2-cacheable) h loads.
//    h fetched ~once per XCD per step: 20 MB/step MALL reads -> ~2.5 MB.
//  - L1's cross-layer shadow read uses flag[0][xcd] if that XCD hosts L0
//    blocks (claim count published after an init grid-barrier), else
//    self-inv. No placement assumptions -> deadlock-free.
//  - stores stay write-through sc0 sc1 (h, out rows, finals): invs may drop
//    dirty L2 lines, so nothing is allowed to be dirty-cached.
// Numerics = validated rounds 2-5: ih single bf16, hh hi+lo W x hi+lo h.

#define TT 512

using short8 = __attribute__((ext_vector_type(8))) short;
using f32x4  = __attribute__((ext_vector_type(4))) float;

__device__ __forceinline__ short f2bf(float f) {
  unsigned u = __float_as_uint(f);
  u = (u + 0x7fffu + ((u >> 16) & 1u)) >> 16;  // RNE
  return (short)u;
}
__device__ __forceinline__ float bf2f(short s) {
  return __uint_as_float(((unsigned)(unsigned short)s) << 16);
}
__device__ __forceinline__ float sigf(float x) { return 1.f / (1.f + __expf(-x)); }
__device__ __forceinline__ float tanh_(float x) { return 1.f - 2.f / (__expf(2.f * x) + 1.f); }

// 8 device-read 16B loads, L2-CACHEABLE (sc0: bypass L1 only).
// Freshness is provided by the per-step leader L2-inv + flag protocol.
__device__ __forceinline__ void ld8_nw(short8* d,
    const short* p0, const short* p1, const short* p2, const short* p3,
    const short* p4, const short* p5, const short* p6, const short* p7) {
  asm volatile(
      "global_load_dwordx4 %0, %8, off sc0\n\t"
      "global_load_dwordx4 %1, %9, off sc0\n\t"
      "global_load_dwordx4 %2, %10, off sc0\n\t"
      "global_load_dwordx4 %3, %11, off sc0\n\t"
      "global_load_dwordx4 %4, %12, off sc0\n\t"
      "global_load_dwordx4 %5, %13, off sc0\n\t"
      "global_load_dwordx4 %6, %14, off sc0\n\t"
      "global_load_dwordx4 %7, %15, off sc0"
      : "=&v"(d[0]), "=&v"(d[1]), "=&v"(d[2]), "=&v"(d[3]),
        "=&v"(d[4]), "=&v"(d[5]), "=&v"(d[6]), "=&v"(d[7])
      : "v"(p0), "v"(p1), "v"(p2), "v"(p3),
        "v"(p4), "v"(p5), "v"(p6), "v"(p7)
      : "memory");
}

// tie a waitcnt (or nothing) to 8 loaded fragments so no use precedes it
#define TIE8(A, CNT)                                                        \
  asm volatile(CNT : "+v"(A[0]), "+v"(A[1]), "+v"(A[2]), "+v"(A[3]),        \
                     "+v"(A[4]), "+v"(A[5]), "+v"(A[6]), "+v"(A[7])         \
               ::"memory")

// coherent write-through stores (reach MALL; never dirty in L2)
__device__ __forceinline__ void stc_short(short* p, short v) {
  asm volatile("global_store_short %0, %1, off sc0 sc1"
               :: "v"(p), "v"((int)v) : "memory");
}
__device__ __forceinline__ void stc_float(float* p, float v) {
  asm volatile("global_store_dword %0, %1, off sc0 sc1"
               :: "v"(p), "v"(v) : "memory");
}

// per-XCD L2 invalidate, completed before return (vmcnt tracks buffer_inv)
__device__ __forceinline__ void l2inv_wait() {
  asm volatile("buffer_inv sc1\n\ts_waitcnt vmcnt(0)" ::: "memory");
}

// ---- x fp32 [64][512][512] -> bf16 in first half of each out row ----
__global__ __launch_bounds__(256) void conv_x(const float* __restrict__ x,
                                              short* __restrict__ xo) {
  size_t g = (size_t)blockIdx.x * 256 + threadIdx.x;  // 2,097,152
  size_t i = g * 8;
  float4 v0 = *(const float4*)(x + i);
  float4 v1 = *(const float4*)(x + i + 4);
  short8 r;
  r[0] = f2bf(v0.x); r[1] = f2bf(v0.y); r[2] = f2bf(v0.z); r[3] = f2bf(v0.w);
  r[4] = f2bf(v1.x); r[5] = f2bf(v1.y); r[6] = f2bf(v1.z); r[7] = f2bf(v1.w);
  *(short8*)(xo + (i >> 9) * 1024 + (i & 511)) = r;
}

// ---- W pack: per-block contiguous LDS image (49152 shorts per (l,j8)) ----
__global__ __launch_bounds__(256) void conv_w(const float* __restrict__ Wih,
                                              const float* __restrict__ Whh,
                                              short* __restrict__ wp) {
  int g = blockIdx.x * 256 + threadIdx.x;  // 0..786431
  int l = g / 393216;
  int rem = g % 393216;
  int j8 = rem / 6144;
  int q8 = rem % 6144;
  int s, hl, bt, c, lane;
  if (q8 < 2048) {
    s = 0; hl = 0;
    int seg = q8 >> 6; bt = seg >> 4; c = seg & 15; lane = q8 & 63;
  } else {
    int q = q8 - 2048;
    s = 1;
    int seg = q >> 6; bt = seg >> 5; c = (seg >> 1) & 15; hl = seg & 1;
    lane = q & 63;
  }
  int r = lane & 15;
  int gg = r >> 2, jj = r & 3;
  int R = gg * 512 + j8 * 8 + bt * 4 + jj;
  int k = c * 32 + (lane >> 4) * 8;
  const float* src = (s ? Whh : Wih) + ((size_t)(l * 2048 + R)) * 512 + k;
  short8 o;
#pragma unroll
  for (int e = 0; e < 8; ++e) {
    float v = src[e];
    short hi = f2bf(v);
    o[e] = hl ? f2bf(v - bf2f(hi)) : hi;
  }
  *(short8*)(wp + (size_t)g * 8) = o;
}

// ---- h0 -> ring slots (L0 init -> slot 3, L1 init -> slot 5) -------------
// hhi/hlo layout: [6 slots][k8=64][b=64][e=8]; slots 0-3 L0 ring, 4-5 L1.
__global__ __launch_bounds__(256) void init_state(const float* __restrict__ h0,
                                                  short* __restrict__ hhi,
                                                  short* __restrict__ hlo,
                                                  unsigned* __restrict__ bar) {
  int i = blockIdx.x * 256 + threadIdx.x;  // 0..65535 [l][b][j]
  int l = i >> 15, bj = i & 32767;
  int b = bj >> 9, j = bj & 511;
  float h = h0[i];
  short hi = f2bf(h);
  int slot = l ? 5 : 3;  // (-1) mod ring
  int o = slot * 32768 + (j >> 3) * 512 + b * 8 + (j & 7);
  hhi[o] = hi;
  hlo[o] = f2bf(h - bf2f(hi));
  // zero 16 KB of barrier/claim/flag state (4096 u32)
  if (blockIdx.x < 16) bar[blockIdx.x * 256 + threadIdx.x] = 0u;
}

// ---- barrier plumbing ----------------------------------------------------
__device__ __forceinline__ unsigned csum(unsigned* c) {
  unsigned s = 0;
#pragma unroll
  for (int r = 0; r < 32; ++r)
    s += __hip_atomic_load(&c[r * 32], __ATOMIC_RELAXED,
                           __HIP_MEMORY_SCOPE_AGENT);
  return s;
}

__device__ __forceinline__ void garrive(unsigned* cnt, int tid, int slot) {
  __syncthreads();  // drains coherent h stores (vmcnt(0) before s_barrier)
  if (tid == 0)
    __hip_atomic_fetch_add(&cnt[slot * 32], 1u, __ATOMIC_RELAXED,
                           __HIP_MEMORY_SCOPE_AGENT);
}

// own-layer wait: detect barrier, then leader-inv or flag-poll, then sync.
__device__ __forceinline__ void gw_main(unsigned* c1, unsigned t1,
                                        unsigned* c2, unsigned t2, int tid,
                                        bool lead, unsigned* flg, unsigned ft) {
  if (tid == 0) {
    for (;;) {
      bool ok = (csum(c1) >= t1);
      if (c2) ok = ok && (csum(c2) >= t2);
      if (ok) break;
      __builtin_amdgcn_s_sleep(1);
    }
    if (lead) {
      l2inv_wait();
      __hip_atomic_store(flg, ft, __ATOMIC_RELAXED, __HIP_MEMORY_SCOPE_AGENT);
    } else {
      while (__hip_atomic_load(flg, __ATOMIC_RELAXED,
                               __HIP_MEMORY_SCOPE_AGENT) < ft)
        __builtin_amdgcn_s_sleep(1);
    }
  }
  __syncthreads();
}

// cross-layer wait (L1 shadow): detect other layer's count, then either poll
// that layer's per-XCD flag (if available) or self-inv.
__device__ __forceinline__ void gw_other(unsigned* c, unsigned tc, int tid,
                                         unsigned* flg, unsigned ft) {
  if (tid == 0) {
    while (csum(c) < tc) __builtin_amdgcn_s_sleep(1);
    if (flg) {
      while (__hip_atomic_load(flg, __ATOMIC_RELAXED,
                               __HIP_MEMORY_SCOPE_AGENT) < ft)
        __builtin_amdgcn_s_sleep(1);
    } else {
      l2inv_wait();
    }
  }
  __syncthreads();
}

// ---- persistent LSTM ----------------------------------------------------
// grid 128 = [layer(2)][j8(64)]; block 512 = 8 waves (kq = wv&3, ah = wv>>2).
// dyn LDS 132096B: [0,98304) W image; [98304,..) float sG[4][32][66].
// bar u32 layout: [0,1024) cnt0; [1024,2048) cnt1; 2048 initCnt;
//                 [2080,2112) claim[L][xcd]; [2176,3200) flag[L][xcd]*32.
__global__ __launch_bounds__(512, 1) void lstm_persist(
    const short* __restrict__ wp, const float* __restrict__ c0,
    const float* __restrict__ bih, const float* __restrict__ bhh,
    short* __restrict__ hhi, short* __restrict__ hlo,
    unsigned* __restrict__ bar, float* __restrict__ out) {
  extern __shared__ char smem[];
  short* lw = (short*)smem;             // 49152 shorts
  float* sG = (float*)(smem + 98304);   // [kq][s][b] stride 66

  const int tid = threadIdx.x;
  const int layer = blockIdx.x >> 6;
  const int j8 = blockIdx.x & 63;
  const int bslot = blockIdx.x & 31;    // 2 blocks per padded counter
  unsigned* cnt0 = bar;
  unsigned* cnt1 = bar + 1024;
  unsigned* icnt = bar + 2048;
  unsigned* claim = bar + 2080;
  unsigned* flags = bar + 2176;
  const int wv = tid >> 6;
  const int kq = wv & 3;
  const int ah = wv >> 2;
  const int lane = tid & 63;
  const int m = lane & 15;
  const int koq = lane >> 4;
  const int cbase = kq << 2;

  // ---- leader election: one block per (layer, XCD) ----
  int xcc;
  asm volatile("s_getreg_b32 %0, hwreg(HW_REG_XCC_ID)" : "=s"(xcc));
  xcc &= 15;
  bool lead = false;
  if (tid == 0)
    lead = (__hip_atomic_fetch_add(&claim[layer * 16 + xcc], 1u,
                                   __ATOMIC_RELAXED,
                                   __HIP_MEMORY_SCOPE_AGENT) == 0u);
  if (tid == 0)
    __hip_atomic_fetch_add(icnt, 1u, __ATOMIC_RELAXED,
                           __HIP_MEMORY_SCOPE_AGENT);

  {  // W slice -> LDS (one-time), overlaps election settling
    const short* src = wp + (size_t)(layer * 64 + j8) * 49152;
    for (int i = tid; i < 6144; i += 512)
      *(short8*)(lw + i * 8) = *(const short8*)(src + i * 8);
  }

  const int sb = tid >> 3, sj = tid & 7;
  const int j = (j8 << 3) + sj;
  float creg = c0[layer * 32768 + sb * 512 + j];
  float hf = 0.f;
  float bsum[4];
#pragma unroll
  for (int g = 0; g < 4; ++g)
    bsum[g] = bih[layer * 2048 + g * 512 + j] + bhh[layer * 2048 + g * 512 + j];

  // init grid barrier: claim counts final after this
  unsigned cl0 = 0;
  if (tid == 0) {
    while (__hip_atomic_load(icnt, __ATOMIC_RELAXED,
                             __HIP_MEMORY_SCOPE_AGENT) < 128u)
      __builtin_amdgcn_s_sleep(1);
    cl0 = __hip_atomic_load(&claim[0 * 16 + xcc], __ATOMIC_RELAXED,
                            __HIP_MEMORY_SCOPE_AGENT);
  }
  __syncthreads();
  unsigned* myflg = flags + (layer * 16 + xcc) * 32;
  unsigned* f0 = flags + (0 * 16 + xcc) * 32;

  const int br0 = ((ah * 2 + 0) << 4) + m;
  const int br1 = ((ah * 2 + 1) << 4) + m;
  const short* xo = (const short*)out;

  f32x4 acc[2][2];

  auto zacc = [&]() {
#pragma unroll
    for (int u = 0; u < 2; ++u)
#pragma unroll
      for (int v = 0; v < 2; ++v) acc[u][v] = f32x4{0.f, 0.f, 0.f, 0.f};
  };

#define PA(rX, cc, br) \
  ((rX) + ((((cbase + (cc)) << 2) + koq) << 9) + (br) * 8)

  // layer-0 ih for a given timestep from bf16 x rows (B-frags from LDS)
  auto ih_l0 = [&](int txt) {
#pragma unroll
    for (int cc = 0; cc < 4; ++cc) {
      const int c = cbase + cc;
      const int k = c * 32 + (koq << 3);
      short8 b0 = *(const short8*)(lw + c * 512 + lane * 8);
      short8 b1 = *(const short8*)(lw + (16 + c) * 512 + lane * 8);
#pragma unroll
      for (int it = 0; it < 2; ++it) {
        const int br = it ? br1 : br0;
        short8 a = *(const short8*)(xo + ((size_t)br * TT + txt) * 1024 + k);
        acc[0][it] = __builtin_amdgcn_mfma_f32_16x16x32_bf16(a, b0, acc[0][it], 0, 0, 0);
        acc[1][it] = __builtin_amdgcn_mfma_f32_16x16x32_bf16(a, b1, acc[1][it], 0, 0, 0);
      }
    }
  };

  // layer-1 ih from an h0 ring slot (hi only; validated numerics).
  // Caller guarantees the preceding wait's inv/flag ordering.
  auto ih_l1 = [&](const short* ph) {
    short8 Ax[8];
    ld8_nw(Ax, PA(ph, 0, br0), PA(ph, 0, br1), PA(ph, 1, br0), PA(ph, 1, br1),
               PA(ph, 2, br0), PA(ph, 2, br1), PA(ph, 3, br0), PA(ph, 3, br1));
    TIE8(Ax, "s_waitcnt vmcnt(0)");
#pragma unroll
    for (int cc = 0; cc < 4; ++cc) {
      const int c = cbase + cc;
      short8 b0 = *(const short8*)(lw + c * 512 + lane * 8);
      short8 b1 = *(const short8*)(lw + (16 + c) * 512 + lane * 8);
#pragma unroll
      for (int it = 0; it < 2; ++it) {
        short8 a = Ax[cc * 2 + it];
        acc[0][it] = __builtin_amdgcn_mfma_f32_16x16x32_bf16(a, b0, acc[0][it], 0, 0, 0);
        acc[1][it] = __builtin_amdgcn_mfma_f32_16x16x32_bf16(a, b1, acc[1][it], 0, 0, 0);
      }
    }
  };

  // shared per-step body: hh (hi+lo), partial reduce, cell update, h store.
  // acc must already hold ih(t). rh/rl = read slot bases; slotOut = write slot.
  auto stepBody = [&](const short* rh, const short* rl, int slotOut, int t) {
    short8 Ah[8], Al[8];
    ld8_nw(Ah, PA(rh, 0, br0), PA(rh, 0, br1), PA(rh, 1, br0), PA(rh, 1, br1),
               PA(rh, 2, br0), PA(rh, 2, br1), PA(rh, 3, br0), PA(rh, 3, br1));
    ld8_nw(Al, PA(rl, 0, br0), PA(rl, 0, br1), PA(rl, 1, br0), PA(rl, 1, br1),
               PA(rl, 2, br0), PA(rl, 2, br1), PA(rl, 3, br0), PA(rl, 3, br1));
    TIE8(Ah, "s_waitcnt vmcnt(0)");
    TIE8(Al, "");

    // ---- hh: hi+lo W x hi+lo h (3 MFMA) ----
#pragma unroll
    for (int cc = 0; cc < 4; ++cc) {
      const int c = cbase + cc;
      short8 bh0 = *(const short8*)(lw + 16384 + (c * 2 + 0) * 512 + lane * 8);
      short8 bl0 = *(const short8*)(lw + 16384 + (c * 2 + 1) * 512 + lane * 8);
      short8 bh1 = *(const short8*)(lw + 16384 + ((16 + c) * 2 + 0) * 512 + lane * 8);
      short8 bl1 = *(const short8*)(lw + 16384 + ((16 + c) * 2 + 1) * 512 + lane * 8);
#pragma unroll
      for (int it = 0; it < 2; ++it) {
        short8 a = Ah[cc * 2 + it];
        short8 al = Al[cc * 2 + it];
        acc[0][it] = __builtin_amdgcn_mfma_f32_16x16x32_bf16(a, bh0, acc[0][it], 0, 0, 0);
        acc[0][it] = __builtin_amdgcn_mfma_f32_16x16x32_bf16(a, bl0, acc[0][it], 0, 0, 0);
        acc[0][it] = __builtin_amdgcn_mfma_f32_16x16x32_bf16(al, bh0, acc[0][it], 0, 0, 0);
        acc[1][it] = __builtin_amdgcn_mfma_f32_16x16x32_bf16(a, bh1, acc[1][it], 0, 0, 0);
        acc[1][it] = __builtin_amdgcn_mfma_f32_16x16x32_bf16(a, bl1, acc[1][it], 0, 0, 0);
        acc[1][it] = __builtin_amdgcn_mfma_f32_16x16x32_bf16(al, bh1, acc[1][it], 0, 0, 0);
      }
    }

    // ---- partials -> sG ----
#pragma unroll
    for (int bt = 0; bt < 2; ++bt)
#pragma unroll
      for (int it = 0; it < 2; ++it) {
        const int srow = bt * 16 + m;
        const int col = ((ah * 2 + it) << 4) + (koq << 2);
#pragma unroll
        for (int r = 0; r < 4; ++r)
          sG[(kq * 32 + srow) * 66 + col + r] = acc[bt][it][r];
      }
    __syncthreads();

    // ---- reduce + cell update ----
    {
      const int bt = sj >> 2, jl = sj & 3;
      float gv[4];
#pragma unroll
      for (int g = 0; g < 4; ++g) {
        const int s = bt * 16 + g * 4 + jl;
        gv[g] = sG[(0 * 32 + s) * 66 + sb] + sG[(1 * 32 + s) * 66 + sb] +
                sG[(2 * 32 + s) * 66 + sb] + sG[(3 * 32 + s) * 66 + sb] +
                bsum[g];
      }
      const float cn = sigf(gv[1]) * creg + sigf(gv[0]) * tanh_(gv[2]);
      const float hn = sigf(gv[3]) * tanh_(cn);
      creg = cn;
      hf = hn;
      const int ho = slotOut * 32768 + (j8 << 9) + tid;
      const short hb = f2bf(hn);
      stc_short(hhi + ho, hb);
      stc_short(hlo + ho, f2bf(hn - bf2f(hb)));
      if (layer)
        stc_float(&out[((size_t)sb * 512 + t) * 512 + j], hn);
    }
  };

  if (layer == 0) {
    // -------- layer 0: own 64-block barrier; 4-slot h0 ring --------
    zacc();
    ih_l0(0);  // prologue: ih(t=0) from x; t=0 h loads hit cold caches
    for (int t = 0; t < TT; ++t) {
      if (t >= 4)
        // own: all L0 stored h0(t-1). guard: all L1 arrived step t-4, so
        // their Ax read of h0(t-4) (slot t&3, about to be overwritten) done.
        gw_main(cnt0, 64u * (unsigned)t, cnt1, 64u * (unsigned)(t - 3), tid,
                lead, myflg, (unsigned)t);
      else if (t >= 1)
        gw_main(cnt0, 64u * (unsigned)t, nullptr, 0u, tid, lead, myflg,
                (unsigned)t);
      const int ps = (t + 3) & 3;  // slot of h0(t-1); t=0 -> 3 = init
      stepBody(hhi + ps * 32768, hlo + ps * 32768, t & 3, t);
      garrive(cnt0, tid, bslot);
      if (t + 1 < TT) {  // overlap next ih with others' wait
        zacc();
        ih_l0(t + 1);
      }
    }
  } else {
    // -------- layer 1: own 64-block barrier; ih in post-arrive overlap ----
    zacc();
    gw_other(cnt0, 64u, tid, cl0 ? f0 : (unsigned*)nullptr, 1u);
    ih_l1(hhi + 0 * 32768);  // h0(0) in slot 0, freshness via flag0/self-inv
    for (int t = 0; t < TT; ++t) {
      if (t >= 1)
        gw_main(cnt1, 64u * (unsigned)t, nullptr, 0u, tid, lead, myflg,
                (unsigned)t);
      const int ps = 4 + ((t + 1) & 1);  // slot of h1(t-1); t=0 -> 5 = init
      stepBody(hhi + ps * 32768, hlo + ps * 32768, 4 + (t & 1), t);
      garrive(cnt1, tid, bslot);
      if (t + 1 < TT) {
        // h0(t+1): wait L0 finished step t+1 (normally already true), with
        // inv coverage on L0's clock. DEADLOCK FIX: L0's leader publishes
        // flags only up to TT-1, so the final read (t+2 == TT) must use
        // the self-inv path (L0 is completely done by then).
        unsigned* fx = (cl0 && (t + 2) < TT) ? f0 : (unsigned*)nullptr;
        gw_other(cnt0, 64u * (unsigned)(t + 2), tid, fx, (unsigned)(t + 2));
        zacc();
        ih_l1(hhi + ((t + 1) & 3) * 32768);
      }
    }
  }

  // finals from registers (write-through: invs must not find dirty lines)
  stc_float(&out[16777216 + layer * 32768 + sb * 512 + j], hf);
  stc_float(&out[16777216 + 65536 + layer * 32768 + sb * 512 + j], creg);
}

// ---- host ---------------------------------------------------------------

extern "C" void kernel_launch(void* const* d_in, const int* in_sizes, int n_in,
                              void* d_out, int out_size, void* d_ws,
                              size_t ws_size, hipStream_t stream) {
  const float* x = (const float*)d_in[0];
  const float* h0 = (const float*)d_in[1];
  const float* c0 = (const float*)d_in[2];
  const float* Wih = (const float*)d_in[3];
  const float* Whh = (const float*)d_in[4];
  const float* bih = (const float*)d_in[5];
  const float* bhh = (const float*)d_in[6];
  float* out = (float*)d_out;

  char* ws = (char*)d_ws;
  short* wp = (short*)(ws + 0);             // 12 MB  fragment-packed W images
  short* hhi = (short*)(ws + 12582912);     // 384 KB h hi [6 slots][k8][b][8]
  short* hlo = (short*)(ws + 12976128);     // 384 KB h lo
  unsigned* bar = (unsigned*)(ws + 13369344);  // 16 KB: counters+claim+flags
  // total ws use: ~12.8 MB

  hipFuncSetAttribute(reinterpret_cast<const void*>(lstm_persist),
                      hipFuncAttributeMaxDynamicSharedMemorySize, 132096);

  conv_x<<<8192, 256, 0, stream>>>(x, (short*)out);
  conv_w<<<3072, 256, 0, stream>>>(Wih, Whh, wp);
  init_state<<<256, 256, 0, stream>>>(h0, hhi, hlo, bar);

  void* args[] = {(void*)&wp,  (void*)&c0,  (void*)&bih, (void*)&bhh,
                  (void*)&hhi, (void*)&hlo, (void*)&bar, (void*)&out};
  hipLaunchCooperativeKernel(reinterpret_cast<void*>(lstm_persist), dim3(128),
                             dim3(512), args, 132096, stream);
}

// Round 6
// 2836.746 us; speedup vs baseline: 1.1116x; 1.0728x over previous
//
#include <hip/hip_runtime.h>
#include <hip/hip_bf16.h>

// LSTM decoder: L=2, B=64, T=512, H=IN=512, gates G=2048 (i,f,g,o).
// Round 11: L2-shared same-layer h exchange + EPOCH invalidation.
//  - r8 (per-step per-block inv): inv storm, regressed. r10 (per-step
//    leader inv + flag): serialization, regressed. Both mechanics failures;
//    FETCH_SIZE (~unique h only) still supports the MALL-BW-bound theory
//    (20 MB/step scattered reads / 5.2us = 3.8 TB/s at the MALL).
//  - r11: same-layer h reads (L0 hh, L1 hh) are sc0 (L2-cacheable);
//    h rings deepened to 16 slots; each block runs buffer_inv INSIDE its
//    barrier wait once per 16 steps. Same-layer skew is barrier-bounded
//    (<1 step), so all reads of h(t-16) complete before anyone passes
//    barrier t-15 < epoch inv at t-14..t -- no stale line can re-enter.
//  - cross-layer path (L1's ih reads h0, lag up to 3 steps) can re-insert
//    lines after a neighbor's inv -> stays sc0 sc1 MALL-direct (never
//    allocates into L2). MALL reads/step: 20 MB -> ~6 MB.
//  - stores remain write-through sc0 sc1 everywhere (h, out rows, finals):
//    invs may drop dirty L2 lines, so nothing is allowed to be dirty.
//  - leaders/claims/flags from r9/r10 deleted; r7 counter plumbing.
// Numerics = validated rounds 2-5: ih single bf16, hh hi+lo W x hi+lo h.

#define TT 512

using short8 = __attribute__((ext_vector_type(8))) short;
using f32x4  = __attribute__((ext_vector_type(4))) float;

__device__ __forceinline__ short f2bf(float f) {
  unsigned u = __float_as_uint(f);
  u = (u + 0x7fffu + ((u >> 16) & 1u)) >> 16;  // RNE
  return (short)u;
}
__device__ __forceinline__ float bf2f(short s) {
  return __uint_as_float(((unsigned)(unsigned short)s) << 16);
}
__device__ __forceinline__ float sigf(float x) { return 1.f / (1.f + __expf(-x)); }
__device__ __forceinline__ float tanh_(float x) { return 1.f - 2.f / (__expf(2.f * x) + 1.f); }

// 8x 16B loads, L2-CACHEABLE (sc0: bypass L1 only). Same-layer h reads:
// freshness guaranteed by ring depth 16 + epoch inv inside the barrier.
__device__ __forceinline__ void ld8_c(short8* d,
    const short* p0, const short* p1, const short* p2, const short* p3,
    const short* p4, const short* p5, const short* p6, const short* p7) {
  asm volatile(
      "global_load_dwordx4 %0, %8, off sc0\n\t"
      "global_load_dwordx4 %1, %9, off sc0\n\t"
      "global_load_dwordx4 %2, %10, off sc0\n\t"
      "global_load_dwordx4 %3, %11, off sc0\n\t"
      "global_load_dwordx4 %4, %12, off sc0\n\t"
      "global_load_dwordx4 %5, %13, off sc0\n\t"
      "global_load_dwordx4 %6, %14, off sc0\n\t"
      "global_load_dwordx4 %7, %15, off sc0"
      : "=&v"(d[0]), "=&v"(d[1]), "=&v"(d[2]), "=&v"(d[3]),
        "=&v"(d[4]), "=&v"(d[5]), "=&v"(d[6]), "=&v"(d[7])
      : "v"(p0), "v"(p1), "v"(p2), "v"(p3),
        "v"(p4), "v"(p5), "v"(p6), "v"(p7)
      : "memory");
}

// 8x 16B loads, MALL-DIRECT (sc0 sc1): cross-layer h0 reads (L1 ih). These
// must NEVER allocate into L2 (lagged inserts would poison epoch coverage).
__device__ __forceinline__ void ld8_d(short8* d,
    const short* p0, const short* p1, const short* p2, const short* p3,
    const short* p4, const short* p5, const short* p6, const short* p7) {
  asm volatile(
      "global_load_dwordx4 %0, %8, off sc0 sc1\n\t"
      "global_load_dwordx4 %1, %9, off sc0 sc1\n\t"
      "global_load_dwordx4 %2, %10, off sc0 sc1\n\t"
      "global_load_dwordx4 %3, %11, off sc0 sc1\n\t"
      "global_load_dwordx4 %4, %12, off sc0 sc1\n\t"
      "global_load_dwordx4 %5, %13, off sc0 sc1\n\t"
      "global_load_dwordx4 %6, %14, off sc0 sc1\n\t"
      "global_load_dwordx4 %7, %15, off sc0 sc1"
      : "=&v"(d[0]), "=&v"(d[1]), "=&v"(d[2]), "=&v"(d[3]),
        "=&v"(d[4]), "=&v"(d[5]), "=&v"(d[6]), "=&v"(d[7])
      : "v"(p0), "v"(p1), "v"(p2), "v"(p3),
        "v"(p4), "v"(p5), "v"(p6), "v"(p7)
      : "memory");
}

// tie a waitcnt (or nothing) to 8 loaded fragments so no use precedes it
#define TIE8(A, CNT)                                                        \
  asm volatile(CNT : "+v"(A[0]), "+v"(A[1]), "+v"(A[2]), "+v"(A[3]),        \
                     "+v"(A[4]), "+v"(A[5]), "+v"(A[6]), "+v"(A[7])         \
               ::"memory")

// coherent write-through stores (reach MALL; never dirty in L2)
__device__ __forceinline__ void stc_short(short* p, short v) {
  asm volatile("global_store_short %0, %1, off sc0 sc1"
               :: "v"(p), "v"((int)v) : "memory");
}
__device__ __forceinline__ void stc_float(float* p, float v) {
  asm volatile("global_store_dword %0, %1, off sc0 sc1"
               :: "v"(p), "v"(v) : "memory");
}

// per-XCD L2 invalidate (tag flash; MALL holds the coherent copy)
__device__ __forceinline__ void l2inv() {
  asm volatile("buffer_inv sc1" ::: "memory");
}

// ---- x fp32 [64][512][512] -> bf16 in first half of each out row ----
__global__ __launch_bounds__(256) void conv_x(const float* __restrict__ x,
                                              short* __restrict__ xo) {
  size_t g = (size_t)blockIdx.x * 256 + threadIdx.x;  // 2,097,152
  size_t i = g * 8;
  float4 v0 = *(const float4*)(x + i);
  float4 v1 = *(const float4*)(x + i + 4);
  short8 r;
  r[0] = f2bf(v0.x); r[1] = f2bf(v0.y); r[2] = f2bf(v0.z); r[3] = f2bf(v0.w);
  r[4] = f2bf(v1.x); r[5] = f2bf(v1.y); r[6] = f2bf(v1.z); r[7] = f2bf(v1.w);
  *(short8*)(xo + (i >> 9) * 1024 + (i & 511)) = r;
}

// ---- W pack: per-block contiguous LDS image (49152 shorts per (l,j8)) ----
__global__ __launch_bounds__(256) void conv_w(const float* __restrict__ Wih,
                                              const float* __restrict__ Whh,
                                              short* __restrict__ wp) {
  int g = blockIdx.x * 256 + threadIdx.x;  // 0..786431
  int l = g / 393216;
  int rem = g % 393216;
  int j8 = rem / 6144;
  int q8 = rem % 6144;
  int s, hl, bt, c, lane;
  if (q8 < 2048) {
    s = 0; hl = 0;
    int seg = q8 >> 6; bt = seg >> 4; c = seg & 15; lane = q8 & 63;
  } else {
    int q = q8 - 2048;
    s = 1;
    int seg = q >> 6; bt = seg >> 5; c = (seg >> 1) & 15; hl = seg & 1;
    lane = q & 63;
  }
  int r = lane & 15;
  int gg = r >> 2, jj = r & 3;
  int R = gg * 512 + j8 * 8 + bt * 4 + jj;
  int k = c * 32 + (lane >> 4) * 8;
  const float* src = (s ? Whh : Wih) + ((size_t)(l * 2048 + R)) * 512 + k;
  short8 o;
#pragma unroll
  for (int e = 0; e < 8; ++e) {
    float v = src[e];
    short hi = f2bf(v);
    o[e] = hl ? f2bf(v - bf2f(hi)) : hi;
  }
  *(short8*)(wp + (size_t)g * 8) = o;
}

// ---- h0 -> ring slots ----------------------------------------------------
// hhi/hlo layout: [32 slots][k8=64][b=64][e=8]; slots 0-15 = L0 ring
// (h0(t) -> slot t&15), slots 16-31 = L1 ring. Init: h(-1) -> slot 15 / 31.
__global__ __launch_bounds__(256) void init_state(const float* __restrict__ h0,
                                                  short* __restrict__ hhi,
                                                  short* __restrict__ hlo,
                                                  unsigned* __restrict__ bar) {
  int i = blockIdx.x * 256 + threadIdx.x;  // 0..65535 [l][b][j]
  int l = i >> 15, bj = i & 32767;
  int b = bj >> 9, j = bj & 511;
  float h = h0[i];
  short hi = f2bf(h);
  int slot = l ? 31 : 15;
  int o = slot * 32768 + (j >> 3) * 512 + b * 8 + (j & 7);
  hhi[o] = hi;
  hlo[o] = f2bf(h - bf2f(hi));
  if (blockIdx.x < 8) bar[blockIdx.x * 256 + threadIdx.x] = 0u;  // cnt0+cnt1
}

// ---- split-phase fence-free per-layer barriers ----
__device__ __forceinline__ unsigned csum(unsigned* c) {
  unsigned s = 0;
#pragma unroll
  for (int r = 0; r < 32; ++r)
    s += __hip_atomic_load(&c[r * 32], __ATOMIC_RELAXED,
                           __HIP_MEMORY_SCOPE_AGENT);
  return s;
}

__device__ __forceinline__ void garrive(unsigned* cnt, int tid, int slot) {
  __syncthreads();  // drains coherent h stores (vmcnt(0) before s_barrier)
  if (tid == 0)
    __hip_atomic_fetch_add(&cnt[slot * 32], 1u, __ATOMIC_RELAXED,
                           __HIP_MEMORY_SCOPE_AGENT);
}

// own-layer wait; doinv=true on epoch steps (t%16==0): per-block L2 inv
// strictly between detect and the h loads. __syncthreads drains the inv
// (compiler emits s_waitcnt vmcnt(0) before s_barrier).
__device__ __forceinline__ void gwait1(unsigned* c1, unsigned t1, int tid,
                                       bool doinv) {
  if (tid == 0) {
    while (csum(c1) < t1) __builtin_amdgcn_s_sleep(1);
  }
  __syncthreads();
  if (doinv) {
    if (tid < 64) l2inv();
    __syncthreads();
  }
}
__device__ __forceinline__ void gwait2(unsigned* c1, unsigned t1,
                                       unsigned* c2, unsigned t2, int tid,
                                       bool doinv) {
  if (tid == 0) {
    for (;;) {
      if (csum(c1) >= t1 && csum(c2) >= t2) break;
      __builtin_amdgcn_s_sleep(1);
    }
  }
  __syncthreads();
  if (doinv) {
    if (tid < 64) l2inv();
    __syncthreads();
  }
}

// cross-layer wait (L1 shadow): detect other layer's count only. The
// subsequent Ax loads are MALL-direct, so no inv/flag is needed here.
__device__ __forceinline__ void gw_other(unsigned* c, unsigned tc, int tid) {
  if (tid == 0) {
    while (csum(c) < tc) __builtin_amdgcn_s_sleep(1);
  }
  __syncthreads();
}

// ---- persistent LSTM ----------------------------------------------------
// grid 128 = [layer(2)][j8(64)]; block 512 = 8 waves (kq = wv&3, ah = wv>>2).
// dyn LDS 132096B: [0,98304) W image; [98304,..) float sG[4][32][66].
// bar u32 layout: [0,1024) cnt0; [1024,2048) cnt1.
__global__ __launch_bounds__(512, 1) void lstm_persist(
    const short* __restrict__ wp, const float* __restrict__ c0,
    const float* __restrict__ bih, const float* __restrict__ bhh,
    short* __restrict__ hhi, short* __restrict__ hlo,
    unsigned* __restrict__ bar, float* __restrict__ out) {
  extern __shared__ char smem[];
  short* lw = (short*)smem;             // 49152 shorts
  float* sG = (float*)(smem + 98304);   // [kq][s][b] stride 66

  const int tid = threadIdx.x;
  const int layer = blockIdx.x >> 6;
  const int j8 = blockIdx.x & 63;
  const int bslot = blockIdx.x & 31;    // 2 blocks per padded counter
  unsigned* cnt0 = bar;
  unsigned* cnt1 = bar + 1024;
  const int wv = tid >> 6;
  const int kq = wv & 3;
  const int ah = wv >> 2;
  const int lane = tid & 63;
  const int m = lane & 15;
  const int koq = lane >> 4;
  const int cbase = kq << 2;

  {  // W slice -> LDS (one-time)
    const short* src = wp + (size_t)(layer * 64 + j8) * 49152;
    for (int i = tid; i < 6144; i += 512)
      *(short8*)(lw + i * 8) = *(const short8*)(src + i * 8);
  }

  const int sb = tid >> 3, sj = tid & 7;
  const int j = (j8 << 3) + sj;
  float creg = c0[layer * 32768 + sb * 512 + j];
  float hf = 0.f;
  float bsum[4];
#pragma unroll
  for (int g = 0; g < 4; ++g)
    bsum[g] = bih[layer * 2048 + g * 512 + j] + bhh[layer * 2048 + g * 512 + j];
  __syncthreads();

  const int br0 = ((ah * 2 + 0) << 4) + m;
  const int br1 = ((ah * 2 + 1) << 4) + m;
  const short* xo = (const short*)out;

  f32x4 acc[2][2];

  auto zacc = [&]() {
#pragma unroll
    for (int u = 0; u < 2; ++u)
#pragma unroll
      for (int v = 0; v < 2; ++v) acc[u][v] = f32x4{0.f, 0.f, 0.f, 0.f};
  };

#define PA(rX, cc, br) \
  ((rX) + ((((cbase + (cc)) << 2) + koq) << 9) + (br) * 8)

  // layer-0 ih for a given timestep from bf16 x rows (B-frags from LDS)
  auto ih_l0 = [&](int txt) {
#pragma unroll
    for (int cc = 0; cc < 4; ++cc) {
      const int c = cbase + cc;
      const int k = c * 32 + (koq << 3);
      short8 b0 = *(const short8*)(lw + c * 512 + lane * 8);
      short8 b1 = *(const short8*)(lw + (16 + c) * 512 + lane * 8);
#pragma unroll
      for (int it = 0; it < 2; ++it) {
        const int br = it ? br1 : br0;
        short8 a = *(const short8*)(xo + ((size_t)br * TT + txt) * 1024 + k);
        acc[0][it] = __builtin_amdgcn_mfma_f32_16x16x32_bf16(a, b0, acc[0][it], 0, 0, 0);
        acc[1][it] = __builtin_amdgcn_mfma_f32_16x16x32_bf16(a, b1, acc[1][it], 0, 0, 0);
      }
    }
  };

  // layer-1 ih from an h0 ring slot (hi only; validated numerics).
  // MALL-direct loads: gated by cnt0, content immutable until slot reuse,
  // which the L0-side guard (cnt1 >= 64*(t-15)) protects.
  auto ih_l1 = [&](const short* ph) {
    short8 Ax[8];
    ld8_d(Ax, PA(ph, 0, br0), PA(ph, 0, br1), PA(ph, 1, br0), PA(ph, 1, br1),
              PA(ph, 2, br0), PA(ph, 2, br1), PA(ph, 3, br0), PA(ph, 3, br1));
    TIE8(Ax, "s_waitcnt vmcnt(0)");
#pragma unroll
    for (int cc = 0; cc < 4; ++cc) {
      const int c = cbase + cc;
      short8 b0 = *(const short8*)(lw + c * 512 + lane * 8);
      short8 b1 = *(const short8*)(lw + (16 + c) * 512 + lane * 8);
#pragma unroll
      for (int it = 0; it < 2; ++it) {
        short8 a = Ax[cc * 2 + it];
        acc[0][it] = __builtin_amdgcn_mfma_f32_16x16x32_bf16(a, b0, acc[0][it], 0, 0, 0);
        acc[1][it] = __builtin_amdgcn_mfma_f32_16x16x32_bf16(a, b1, acc[1][it], 0, 0, 0);
      }
    }
  };

  // shared per-step body: hh (hi+lo), partial reduce, cell update, h store.
  // acc must already hold ih(t). rh/rl = read slot bases (L2-cached loads);
  // slotOut = write slot.
  auto stepBody = [&](const short* rh, const short* rl, int slotOut, int t) {
    short8 Ah[8], Al[8];
    ld8_c(Ah, PA(rh, 0, br0), PA(rh, 0, br1), PA(rh, 1, br0), PA(rh, 1, br1),
              PA(rh, 2, br0), PA(rh, 2, br1), PA(rh, 3, br0), PA(rh, 3, br1));
    ld8_c(Al, PA(rl, 0, br0), PA(rl, 0, br1), PA(rl, 1, br0), PA(rl, 1, br1),
              PA(rl, 2, br0), PA(rl, 2, br1), PA(rl, 3, br0), PA(rl, 3, br1));
    TIE8(Ah, "s_waitcnt vmcnt(0)");
    TIE8(Al, "");

    // ---- hh: hi+lo W x hi+lo h (3 MFMA) ----
#pragma unroll
    for (int cc = 0; cc < 4; ++cc) {
      const int c = cbase + cc;
      short8 bh0 = *(const short8*)(lw + 16384 + (c * 2 + 0) * 512 + lane * 8);
      short8 bl0 = *(const short8*)(lw + 16384 + (c * 2 + 1) * 512 + lane * 8);
      short8 bh1 = *(const short8*)(lw + 16384 + ((16 + c) * 2 + 0) * 512 + lane * 8);
      short8 bl1 = *(const short8*)(lw + 16384 + ((16 + c) * 2 + 1) * 512 + lane * 8);
#pragma unroll
      for (int it = 0; it < 2; ++it) {
        short8 a = Ah[cc * 2 + it];
        short8 al = Al[cc * 2 + it];
        acc[0][it] = __builtin_amdgcn_mfma_f32_16x16x32_bf16(a, bh0, acc[0][it], 0, 0, 0);
        acc[0][it] = __builtin_amdgcn_mfma_f32_16x16x32_bf16(a, bl0, acc[0][it], 0, 0, 0);
        acc[0][it] = __builtin_amdgcn_mfma_f32_16x16x32_bf16(al, bh0, acc[0][it], 0, 0, 0);
        acc[1][it] = __builtin_amdgcn_mfma_f32_16x16x32_bf16(a, bh1, acc[1][it], 0, 0, 0);
        acc[1][it] = __builtin_amdgcn_mfma_f32_16x16x32_bf16(a, bl1, acc[1][it], 0, 0, 0);
        acc[1][it] = __builtin_amdgcn_mfma_f32_16x16x32_bf16(al, bh1, acc[1][it], 0, 0, 0);
      }
    }

    // ---- partials -> sG ----
#pragma unroll
    for (int bt = 0; bt < 2; ++bt)
#pragma unroll
      for (int it = 0; it < 2; ++it) {
        const int srow = bt * 16 + m;
        const int col = ((ah * 2 + it) << 4) + (koq << 2);
#pragma unroll
        for (int r = 0; r < 4; ++r)
          sG[(kq * 32 + srow) * 66 + col + r] = acc[bt][it][r];
      }
    __syncthreads();

    // ---- reduce + cell update ----
    {
      const int bt = sj >> 2, jl = sj & 3;
      float gv[4];
#pragma unroll
      for (int g = 0; g < 4; ++g) {
        const int s = bt * 16 + g * 4 + jl;
        gv[g] = sG[(0 * 32 + s) * 66 + sb] + sG[(1 * 32 + s) * 66 + sb] +
                sG[(2 * 32 + s) * 66 + sb] + sG[(3 * 32 + s) * 66 + sb] +
                bsum[g];
      }
      const float cn = sigf(gv[1]) * creg + sigf(gv[0]) * tanh_(gv[2]);
      const float hn = sigf(gv[3]) * tanh_(cn);
      creg = cn;
      hf = hn;
      const int ho = slotOut * 32768 + (j8 << 9) + tid;
      const short hb = f2bf(hn);
      stc_short(hhi + ho, hb);
      stc_short(hlo + ho, f2bf(hn - bf2f(hb)));
      if (layer)
        stc_float(&out[((size_t)sb * 512 + t) * 512 + j], hn);
    }
  };

  if (layer == 0) {
    // -------- layer 0: 16-slot h0 ring; epoch inv at t%16==0 --------
    zacc();
    ih_l0(0);  // prologue: ih(t=0) from x
    for (int t = 0; t < TT; ++t) {
      if (t >= 16)
        // own: all L0 stored h0(t-1). guard: all L1 arrived t-15, so their
        // direct Ax reads of h0(t-16) (slot t&15, being overwritten) done.
        gwait2(cnt0, 64u * (unsigned)t, cnt1, 64u * (unsigned)(t - 15), tid,
               (t & 15) == 0);
      else if (t >= 1)
        gwait1(cnt0, 64u * (unsigned)t, tid, false);
      const int ps = (t + 15) & 15;  // slot of h0(t-1); t=0 -> 15 = init
      stepBody(hhi + ps * 32768, hlo + ps * 32768, t & 15, t);
      garrive(cnt0, tid, bslot);
      if (t + 1 < TT) {  // overlap next ih with others' wait
        zacc();
        ih_l0(t + 1);
      }
    }
  } else {
    // -------- layer 1: 16-slot h1 ring; ih (MALL-direct) in overlap ------
    zacc();
    gw_other(cnt0, 64u, tid);  // L0 finished step 0 -> h0(0) in slot 0
    ih_l1(hhi + 0 * 32768);
    for (int t = 0; t < TT; ++t) {
      if (t >= 1)
        gwait1(cnt1, 64u * (unsigned)t, tid, ((t & 15) == 0) && t >= 16);
      const int ps = 16 + ((t + 15) & 15);  // slot of h1(t-1); t=0 -> 31
      stepBody(hhi + ps * 32768, hlo + ps * 32768, 16 + (t & 15), t);
      garrive(cnt1, tid, bslot);
      if (t + 1 < TT) {
        // h0(t+1): wait L0 finished step t+1 (normally already true), then
        // direct Ax + ih in the shadow of stragglers. No inv needed.
        gw_other(cnt0, 64u * (unsigned)(t + 2), tid);
        zacc();
        ih_l1(hhi + ((t + 1) & 15) * 32768);
      }
    }
  }

  // finals from registers (write-through: invs must not find dirty lines)
  stc_float(&out[16777216 + layer * 32768 + sb * 512 + j], hf);
  stc_float(&out[16777216 + 65536 + layer * 32768 + sb * 512 + j], creg);
}

// ---- host ---------------------------------------------------------------

extern "C" void kernel_launch(void* const* d_in, const int* in_sizes, int n_in,
                              void* d_out, int out_size, void* d_ws,
                              size_t ws_size, hipStream_t stream) {
  const float* x = (const float*)d_in[0];
  const float* h0 = (const float*)d_in[1];
  const float* c0 = (const float*)d_in[2];
  const float* Wih = (const float*)d_in[3];
  const float* Whh = (const float*)d_in[4];
  const float* bih = (const float*)d_in[5];
  const float* bhh = (const float*)d_in[6];
  float* out = (float*)d_out;

  char* ws = (char*)d_ws;
  short* wp = (short*)(ws + 0);             // 12 MB  fragment-packed W images
  short* hhi = (short*)(ws + 12582912);     // 2 MB h hi [32 slots][k8][b][8]
  short* hlo = (short*)(ws + 14680064);     // 2 MB h lo
  unsigned* bar = (unsigned*)(ws + 16777216);  // 8 KB: 2 x 32 padded counters
  // total ws use: ~16.8 MB

  hipFuncSetAttribute(reinterpret_cast<const void*>(lstm_persist),
                      hipFuncAttributeMaxDynamicSharedMemorySize, 132096);

  conv_x<<<8192, 256, 0, stream>>>(x, (short*)out);
  conv_w<<<3072, 256, 0, stream>>>(Wih, Whh, wp);
  init_state<<<256, 256, 0, stream>>>(h0, hhi, hlo, bar);

  void* args[] = {(void*)&wp,  (void*)&c0,  (void*)&bih, (void*)&bhh,
                  (void*)&hhi, (void*)&hlo, (void*)&bar, (void*)&out};
  hipLaunchCooperativeKernel(reinterpret_cast<void*>(lstm_persist), dim3(128),
                             dim3(512), args, 132096, stream);
}